// Round 17
// baseline (225.033 us; speedup 1.0000x reference)
//
#include <hip/hip_runtime.h>
#include <math.h>

// Fixed-point LeNet, B=2048. R26 = R25 resubmitted (R25's bench died on
// container-acquire infrastructure, not the kernel — no data collected).
// Thesis under test: co-pairing, ALL array indices compile-time.
// R24 post-mortem: counters byte-identical to R23 (VGPR=52, FETCH 27.9MB,
// WRITE 135MB) -> macro-epilogue fix addressed the wrong mechanism. Real
// cause (rule #20): phase A's "#pragma unroll 1" p-loop indexes
// wregA[p*5+q] with RUNTIME p -> compiler can't prove the element ->
// wregA/wregB (56 floats) live in scratch, re-read every iteration.
// R21 was immune (fully-unrolled loops = compile-time p).
// This kernel: p-loops macro-expanded as literal steps A_STEP(0..4) /
// B_STEP(0..4): every wreg index compile-time; fences between A-steps cap
// in-flight x-loads at 16. FMA order unchanged -> bit-identical outputs.
// Live: phase A ~104, phase B ~90 regs < 128 cap (launch_bounds(256,4)).
// Diagnostic: VGPR_Count must rise to ~100 (arrays in registers again).
//
// Output layout (fp32, concatenated flat in reference return order):
//   logp[2048,10], conv1_in[2048,784], conv1_out[2048,5760],
//   conv2_in[2048,1440], conv2_out[2048,1280], fc1_in[2048,320],
//   fc1_out[2048,50], fc2_in[2048,50], fc2_out[2048,10]

#define NB 2048

#define OFF_LOGP   0
#define OFF_C1IN   (OFF_LOGP  + NB*10)
#define OFF_C1OUT  (OFF_C1IN  + NB*784)
#define OFF_C2IN   (OFF_C1OUT + NB*5760)
#define OFF_C2OUT  (OFF_C2IN  + NB*1440)
#define OFF_FC1IN  (OFF_C2OUT + NB*1280)
#define OFF_FC1OUT (OFF_FC1IN + NB*320)
#define OFF_FC2IN  (OFF_FC1OUT+ NB*50)
#define OFF_FC2OUT (OFF_FC2IN + NB*50)

#define MAGIC_F 12582912.0f   // 1.5 * 2^23

// Workspace layout (floats): pre-quantized weights, written by k0_prep.
// IDENTICAL to R17-R21 (proven; 27270 floats = 106.5 KB).
#define WS_WT1 0         // [320][64] transposed fw1 (j>=50 -> 0)
#define WS_B1  20480     // [64]
#define WS_WT2 20544     // [50][16] transposed fw2 (j>=10 -> 0)
#define WS_B2  21344     // [16]
#define WS_CW2 21360     // [20*10][28] padded conv2 rows, quant(w)*256 (col>=25 -> 0)
#define WS_CB2 26960     // [20] quant(b)*256
#define WS_CW1 26980     // [10][28] padded conv1 rows, quant(w)*256
#define WS_CB1 27260     // [10] quant(b)*256   (total 27270 floats)

__device__ __forceinline__ float clamp8(float v) {
    return __builtin_amdgcn_fmed3f(v, -8.0f, 7.0f);
}

// ---------------- K0: weight pre-quantization (52 small blocks) ----------------
__global__ __launch_bounds__(256)
void k0_prep(const float* __restrict__ cw1, const float* __restrict__ cb1,
             const float* __restrict__ cw2, const float* __restrict__ cb2,
             const float* __restrict__ fw1, const float* __restrict__ fb1,
             const float* __restrict__ fw2, const float* __restrict__ fb2,
             float* __restrict__ ws)
{
    const int t = threadIdx.x, b = blockIdx.x;
    if (b < 50) {
        // wT1 row j=b: coalesced read fw1[b*320 + i], scattered (cheap) write.
        const float* src = fw1 + b * 320;
        for (int i = t; i < 320; i += 256)
            ws[WS_WT1 + i * 64 + b] = clamp8(rintf(src[i] * 256.0f) * (1.0f / 256.0f));
    } else if (b == 50) {
        for (int idx = t; idx < 320 * 14; idx += 256) {     // zero cols 50..63
            int i = idx / 14, j = 50 + idx % 14;
            ws[WS_WT1 + i * 64 + j] = 0.0f;
        }
        for (int idx = t; idx < 800; idx += 256) {          // wT2[50][16]
            int k = idx >> 4, j = idx & 15;
            ws[WS_WT2 + idx] = (j < 10) ? clamp8(rintf(fw2[j * 50 + k] * 256.0f) * (1.0f / 256.0f)) : 0.0f;
        }
        if (t < 64) ws[WS_B1 + t] = (t < 50) ? clamp8(rintf(fb1[t] * 256.0f) * (1.0f / 256.0f)) : 0.0f;
        if (t < 16) ws[WS_B2 + t] = (t < 10) ? clamp8(rintf(fb2[t] * 256.0f) * (1.0f / 256.0f)) : 0.0f;
    } else {   // b == 51: conv weights, padded [rows][28], x256
        for (int idx = t; idx < 5600; idx += 256) {
            int cc = idx / 28, col = idx % 28;
            ws[WS_CW2 + idx] = (col < 25) ? rintf(cw2[cc * 25 + col] * 256.0f) : 0.0f;
        }
        if (t < 20) ws[WS_CB2 + t] = rintf(cb2[t] * 256.0f);
        for (int idx = t; idx < 280; idx += 256) {
            int cc = idx / 28, col = idx % 28;
            ws[WS_CW1 + idx] = (col < 25) ? rintf(cw1[cc * 25 + col] * 256.0f) : 0.0f;
        }
        if (t >= 32 && t < 42) ws[WS_CB1 + (t - 32)] = rintf(cb1[t - 32] * 256.0f);
    }
}

// ---- Phase-A conv step, literal P (all wreg indices compile-time) ----
#define A_STEP(P) do {                                                            \
    const float* row_ = s_x + (i + (P)) * 28 + 12 * jh;                           \
    float4 x0_ = *(const float4*)(row_);                                          \
    float4 x1_ = *(const float4*)(row_ + 4);                                      \
    float4 x2_ = *(const float4*)(row_ + 8);                                      \
    float4 x3_ = *(const float4*)(row_ + 12);                                     \
    float xr_[16] = { x0_.x, x0_.y, x0_.z, x0_.w, x1_.x, x1_.y, x1_.z, x1_.w,     \
                      x2_.x, x2_.y, x2_.z, x2_.w, x3_.x, x3_.y, x3_.z, x3_.w };   \
    _Pragma("unroll")                                                             \
    for (int q = 0; q < 5; q++) {                                                 \
        const float wA_ = wregA[(P) * 5 + q];                                     \
        const float wB_ = wregB[(P) * 5 + q];                                     \
        _Pragma("unroll")                                                         \
        for (int j = 0; j < 12; j++) {                                            \
            accA[j] = fmaf(xr_[q + j], wA_, accA[j]);                             \
            accB[j] = fmaf(xr_[q + j], wB_, accB[j]);                             \
        }                                                                         \
    }                                                                             \
} while (0)

// ---- Phase-B conv step, literal P ----
#define B_STEP(P) do {                                                            \
    const float* row_ = xb + (i2 + (P)) * 12;                                     \
    float4 a4_ = *(const float4*)(row_);                                          \
    float4 b4_ = *(const float4*)(row_ + 4);                                      \
    float4 c4_ = *(const float4*)(row_ + 8);                                      \
    float xr_[12] = { a4_.x, a4_.y, a4_.z, a4_.w, b4_.x, b4_.y, b4_.z, b4_.w,     \
                      c4_.x, c4_.y, c4_.z, c4_.w };                               \
    _Pragma("unroll")                                                             \
    for (int q = 0; q < 5; q++) {                                                 \
        const float wA_ = wregA[(P) * 5 + q];                                     \
        const float wB_ = wregB[(P) * 5 + q];                                     \
        _Pragma("unroll")                                                         \
        for (int j = 0; j < 8; j++) {                                             \
            accA[j] = fmaf(xr_[q + j], wA_, accA[j]);                             \
            accB[j] = fmaf(xr_[q + j], wB_, accB[j]);                             \
        }                                                                         \
    }                                                                             \
} while (0)

// Phase-A epilogue (proven R24): direct indexing, no address escape.
#define EPI_A(CO, ACC) do {                                                       \
    const int co_ = (CO);                                                         \
    const float C_ = MAGIC_F - ws[WS_CB1 + co_];                                  \
    float v_[12];                                                                 \
    _Pragma("unroll")                                                             \
    for (int j = 0; j < 12; j++) v_[j] = (ACC[j] - C_) * (1.0f / 256.0f);         \
    float* gdst_ = out + OFF_C1OUT + (size_t)img * 5760 + co_ * 576 + i * 24 + 12 * jh; \
    _Pragma("unroll")                                                             \
    for (int k = 0; k < 3; k++) {                                                 \
        float4 st_ = { v_[4*k], v_[4*k+1], v_[4*k+2], v_[4*k+3] };                \
        *(float4*)(gdst_ + 4 * k) = st_;                                          \
    }                                                                             \
    float m_[6];                                                                  \
    _Pragma("unroll")                                                             \
    for (int j2 = 0; j2 < 6; j2++) m_[j2] = fmaxf(v_[2*j2], v_[2*j2+1]);          \
    float pm_[6];                                                                 \
    _Pragma("unroll")                                                             \
    for (int j2 = 0; j2 < 6; j2++) pm_[j2] = __shfl_xor(m_[j2], 2);               \
    if ((ii & 1) == 0) {                                                          \
        float pr_[6];                                                             \
        _Pragma("unroll")                                                         \
        for (int j2 = 0; j2 < 6; j2++)                                            \
            pr_[j2] = fmaxf(fmaxf(m_[j2], pm_[j2]), 0.0f);                        \
        const int o_ = co_ * 144 + (i >> 1) * 12 + 6 * jh;                        \
        float* g_ = out + OFF_C2IN + (size_t)img * 1440 + o_;                     \
        _Pragma("unroll")                                                         \
        for (int k = 0; k < 3; k++) {                                             \
            float2 st_ = { pr_[2*k], pr_[2*k+1] };                                \
            *(float2*)(g_ + 2 * k) = st_;                                         \
            *(float2*)(s_p1 + o_ + 2 * k) = st_;                                  \
        }                                                                         \
    }                                                                             \
} while (0)

// Phase-B epilogue (proven R24).
#define EPI_B(CO, ACC) do {                                                       \
    const int co_ = (CO);                                                         \
    float s_[8];                                                                  \
    _Pragma("unroll")                                                             \
    for (int j = 0; j < 8; j++) s_[j] = ACC[j] - MAGIC_F;                         \
    _Pragma("unroll")                                                             \
    for (int j = 0; j < 8; j++) s_[j] += __shfl_xor(s_[j], 1);                    \
    const float b2_ = ws[WS_CB2 + co_];                                           \
    float v_[8];                                                                  \
    _Pragma("unroll")                                                             \
    for (int j = 0; j < 8; j++) v_[j] = (s_[j] + b2_) * (1.0f / 256.0f);          \
    float m_[4], pm_[4];                                                          \
    _Pragma("unroll")                                                             \
    for (int c = 0; c < 4; c++) m_[c] = fmaxf(v_[2*c], v_[2*c+1]);                \
    _Pragma("unroll")                                                             \
    for (int c = 0; c < 4; c++) pm_[c] = __shfl_xor(m_[c], 2);                    \
    if (ch == 0) {                                                                \
        float4 st0_ = { v_[0], v_[1], v_[2], v_[3] };                             \
        float4 st1_ = { v_[4], v_[5], v_[6], v_[7] };                             \
        float* cdst_ = out + OFF_C2OUT + (size_t)img * 1280 + co_ * 64 + i2 * 8;  \
        *(float4*)(cdst_)     = st0_;                                             \
        *(float4*)(cdst_ + 4) = st1_;                                             \
        if ((i2 & 1) == 0) {                                                      \
            float4 pr_ = { fmaxf(fmaxf(m_[0], pm_[0]), 0.0f),                     \
                           fmaxf(fmaxf(m_[1], pm_[1]), 0.0f),                     \
                           fmaxf(fmaxf(m_[2], pm_[2]), 0.0f),                     \
                           fmaxf(fmaxf(m_[3], pm_[3]), 0.0f) };                   \
            const int o_ = co_ * 16 + (i2 >> 1) * 4;                              \
            *(float4*)(out + OFF_FC1IN + (size_t)img * 320 + o_) = pr_;           \
            float4 prc_ = { clamp8(pr_.x), clamp8(pr_.y), clamp8(pr_.z), clamp8(pr_.w) }; \
            *(float4*)(s_x + o_) = prc_;                                          \
        }                                                                         \
    }                                                                             \
} while (0)

// ---------------- K12W: whole net, FOUR waves per image, co-paired ----------------
// block=256 (4 waves), grid = NB = 2048.
// Phase A: lane (L<60): c5=L/12, r=L%12, ii=r>>1, jh=r&1, i=6wv+ii;
//   computes co=c5 AND c5+5 in one x-pass (literal steps). Pool partner L^2.
// Phase B: groups g=t>>4 in 0..9 own co pair (g, g+10); ch=t&1, i2=(t>>1)&7;
//   reduce partner t^1, pool partner t^2. Groups 10..15 idle.
// Phase C: fc1+fc2+softmax on wave 0 (proven k3 body).
__global__ __launch_bounds__(256, 4)
void k12w(const float* __restrict__ x, const float* __restrict__ ws,
          float* __restrict__ out)
{
    __shared__ __align__(16) float s_x[784];    // image; [0..320) reused as fc1in
    __shared__ __align__(16) float s_p1[1440];  // pool1 out = conv2 in

    const int t   = threadIdx.x;
    const int img = blockIdx.x;
    const int wv  = t >> 6;
    const int L   = t & 63;

    {   // input staging: quantize once, write c1in + LDS
        const float* xg = x + (size_t)img * 784;
        float* c1in_g = out + OFF_C1IN + (size_t)img * 784;
        for (int i = t; i < 784; i += 256) {
            float v = rintf(xg[i] * 256.0f) * (1.0f / 256.0f);
            s_x[i] = v;
            c1in_g[i] = v;
        }
    }
    __syncthreads();

    // ================= phase A: conv1 + pool1, co-paired =================
    if (L < 60) {
        const int c5 = L / 12;         // 0..4
        const int r  = L % 12;
        const int ii = r >> 1;         // 0..5
        const int jh = r & 1;          // cols [12*jh, 12*jh+12)
        const int i  = wv * 6 + ii;    // 0..23

        float wregA[28], wregB[28];    // proven [*][28] 7xb128 pattern, x2 co
        {
            const float* wa = ws + WS_CW1 + c5 * 28;
            const float* wb = ws + WS_CW1 + (c5 + 5) * 28;
            #pragma unroll
            for (int k = 0; k < 7; k++) {
                float4 a4 = *(const float4*)(wa + 4 * k);
                float4 b4 = *(const float4*)(wb + 4 * k);
                wregA[4*k]=a4.x; wregA[4*k+1]=a4.y; wregA[4*k+2]=a4.z; wregA[4*k+3]=a4.w;
                wregB[4*k]=b4.x; wregB[4*k+1]=b4.y; wregB[4*k+2]=b4.z; wregB[4*k+3]=b4.w;
            }
        }

        float accA[12], accB[12];
        #pragma unroll
        for (int j = 0; j < 12; j++) { accA[j] = MAGIC_F; accB[j] = MAGIC_F; }

        A_STEP(0);
        asm volatile("" ::: "memory");   // cap in-flight x-loads at one step
        A_STEP(1);
        asm volatile("" ::: "memory");
        A_STEP(2);
        asm volatile("" ::: "memory");
        A_STEP(3);
        asm volatile("" ::: "memory");
        A_STEP(4);

        EPI_A(c5, accA);
        EPI_A(c5 + 5, accB);
    }
    __syncthreads();   // s_p1 complete (all 10 ci)

    // ================= phase B: conv2 + pool2, co-paired (groups 0..9) =================
    if ((t >> 4) < 10) {
        const int g  = t >> 4;         // 0..9 -> co pair (g, g+10)
        const int ch = t & 1;          // ci-half
        const int i2 = (t >> 1) & 7;

        float accA[8], accB[8];
        #pragma unroll
        for (int j = 0; j < 8; j++) { accA[j] = MAGIC_F; accB[j] = MAGIC_F; }

        #pragma unroll 1
        for (int cc = 0; cc < 5; cc++) {
            asm volatile("" ::: "memory");   // proven-safe insurance vs load batching
            const int ci = ch * 5 + cc;

            float wregA[28], wregB[28];      // proven [cc][28] 7xb128 pattern, x2 co
            {
                const float* wa = ws + WS_CW2 + (g * 10 + ci) * 28;
                const float* wb = ws + WS_CW2 + ((g + 10) * 10 + ci) * 28;
                #pragma unroll
                for (int k = 0; k < 7; k++) {
                    float4 a4 = *(const float4*)(wa + 4 * k);
                    float4 b4 = *(const float4*)(wb + 4 * k);
                    wregA[4*k]=a4.x; wregA[4*k+1]=a4.y; wregA[4*k+2]=a4.z; wregA[4*k+3]=a4.w;
                    wregB[4*k]=b4.x; wregB[4*k+1]=b4.y; wregB[4*k+2]=b4.z; wregB[4*k+3]=b4.w;
                }
            }
            const float* xb = s_p1 + ci * 144;
            B_STEP(0);
            B_STEP(1);
            B_STEP(2);
            B_STEP(3);
            B_STEP(4);
        }

        EPI_B(g, accA);
        EPI_B(g + 10, accB);
    }
    __syncthreads();   // fc1in (s_x[0..320)) complete

    // ================= phase C: fc1 + fc2 + log_softmax (wave 0 only) =================
    if (wv == 0) {
        const float* sf = s_x;
        float acc = ws[WS_B1 + L];
        #pragma unroll 8
        for (int k = 0; k < 320; k++)
            acc = fmaf(sf[k], ws[WS_WT1 + k * 64 + L], acc);   // LDS broadcast + 256B coalesced
        float o1 = rintf(clamp8(acc) * 256.0f) * (1.0f / 256.0f);
        float r1 = fmaxf(o1, 0.0f);
        if (L < 50) {
            out[OFF_FC1OUT + (size_t)img * 50 + L] = o1;
            out[OFF_FC2IN  + (size_t)img * 50 + L] = r1;
        }
        float yc = clamp8(r1);                 // valid on lanes 0..49

        float acc2 = ws[WS_B2 + (L & 15)];
        #pragma unroll 10
        for (int k = 0; k < 50; k++) {
            float yk = __shfl(yc, k);
            acc2 = fmaf(yk, ws[WS_WT2 + k * 16 + (L & 15)], acc2);
        }
        float o2 = rintf(clamp8(acc2) * 256.0f) * (1.0f / 256.0f);
        if (L < 10) out[OFF_FC2OUT + (size_t)img * 10 + L] = o2;

        float vmx = (L < 10) ? o2 : -3.0e38f;
        #pragma unroll
        for (int d = 1; d < 16; d <<= 1)
            vmx = fmaxf(vmx, __shfl_xor(vmx, d, 16));
        float e = (L < 10) ? expf(o2 - vmx) : 0.0f;
        #pragma unroll
        for (int d = 1; d < 16; d <<= 1)
            e += __shfl_xor(e, d, 16);
        float lse = vmx + logf(e);
        if (L < 10) out[OFF_LOGP + (size_t)img * 10 + L] = o2 - lse;
    }
}

extern "C" void kernel_launch(void* const* d_in, const int* in_sizes, int n_in,
                              void* d_out, int out_size, void* d_ws, size_t ws_size,
                              hipStream_t stream) {
    const float* x   = (const float*)d_in[0];
    const float* cw1 = (const float*)d_in[1];
    const float* cb1 = (const float*)d_in[2];
    const float* cw2 = (const float*)d_in[3];
    const float* cb2 = (const float*)d_in[4];
    const float* fw1 = (const float*)d_in[5];
    const float* fb1 = (const float*)d_in[6];
    const float* fw2 = (const float*)d_in[7];
    const float* fb2 = (const float*)d_in[8];
    float* o  = (float*)d_out;
    float* ws = (float*)d_ws;

    k0_prep<<<52, 256, 0, stream>>>(cw1, cb1, cw2, cb2, fw1, fb1, fw2, fb2, ws);
    k12w   <<<NB, 256, 0, stream>>>(x, ws, o);
}

// Round 18
// 154.994 us; speedup vs baseline: 1.4519x; 1.4519x over previous
//
#include <hip/hip_runtime.h>
#include <math.h>

// Fixed-point LeNet, B=2048. R27 = R21 (best verified: k12w 62.1us, total
// 153.4us) with ONE change: launch_bounds (256,8)->(256,4).
// Rationale: R21's VGPR_Count=32 + FETCH 6.6MB (vs R19's (128,4) build:
// VGPR=56, FETCH 3.8MB) shows the 64-VGPR cap of (256,8) forces ~3MB of
// wreg/acc scratch spill sitting on the inner-loop critical path. R20
// proved occupancy >4 waves/SIMD is duration-flat, so the (256,8) headroom
// is unused. (256,4) = 128-VGPR cap: wreg[28]+acc[12] fit in registers.
// Co-pairing arc (R22-R26) abandoned per decision rule: 1 correctness
// failure + 3 compiler-spill regressions; this compiler won't allocate the
// dual-acc/dual-wreg live set to registers.
//
// Output layout (fp32, concatenated flat in reference return order):
//   logp[2048,10], conv1_in[2048,784], conv1_out[2048,5760],
//   conv2_in[2048,1440], conv2_out[2048,1280], fc1_in[2048,320],
//   fc1_out[2048,50], fc2_in[2048,50], fc2_out[2048,10]

#define NB 2048

#define OFF_LOGP   0
#define OFF_C1IN   (OFF_LOGP  + NB*10)
#define OFF_C1OUT  (OFF_C1IN  + NB*784)
#define OFF_C2IN   (OFF_C1OUT + NB*5760)
#define OFF_C2OUT  (OFF_C2IN  + NB*1440)
#define OFF_FC1IN  (OFF_C2OUT + NB*1280)
#define OFF_FC1OUT (OFF_FC1IN + NB*320)
#define OFF_FC2IN  (OFF_FC1OUT+ NB*50)
#define OFF_FC2OUT (OFF_FC2IN + NB*50)

#define MAGIC_F 12582912.0f   // 1.5 * 2^23

// Workspace layout (floats): pre-quantized weights, written by k0_prep.
#define WS_WT1 0         // [320][64] transposed fw1 (j>=50 -> 0)
#define WS_B1  20480     // [64]
#define WS_WT2 20544     // [50][16] transposed fw2 (j>=10 -> 0)
#define WS_B2  21344     // [16]
#define WS_CW2 21360     // [20*10][28] padded conv2 rows, quant(w)*256 (col>=25 -> 0)
#define WS_CB2 26960     // [20] quant(b)*256
#define WS_CW1 26980     // [10][28] padded conv1 rows, quant(w)*256
#define WS_CB1 27260     // [10] quant(b)*256   (total 27270 floats)

__device__ __forceinline__ float clamp8(float v) {
    return __builtin_amdgcn_fmed3f(v, -8.0f, 7.0f);
}

// ---------------- K0: weight pre-quantization (52 small blocks) ----------------
__global__ __launch_bounds__(256)
void k0_prep(const float* __restrict__ cw1, const float* __restrict__ cb1,
             const float* __restrict__ cw2, const float* __restrict__ cb2,
             const float* __restrict__ fw1, const float* __restrict__ fb1,
             const float* __restrict__ fw2, const float* __restrict__ fb2,
             float* __restrict__ ws)
{
    const int t = threadIdx.x, b = blockIdx.x;
    if (b < 50) {
        // wT1 row j=b: coalesced read fw1[b*320 + i], scattered (cheap) write.
        const float* src = fw1 + b * 320;
        for (int i = t; i < 320; i += 256)
            ws[WS_WT1 + i * 64 + b] = clamp8(rintf(src[i] * 256.0f) * (1.0f / 256.0f));
    } else if (b == 50) {
        for (int idx = t; idx < 320 * 14; idx += 256) {     // zero cols 50..63
            int i = idx / 14, j = 50 + idx % 14;
            ws[WS_WT1 + i * 64 + j] = 0.0f;
        }
        for (int idx = t; idx < 800; idx += 256) {          // wT2[50][16]
            int k = idx >> 4, j = idx & 15;
            ws[WS_WT2 + idx] = (j < 10) ? clamp8(rintf(fw2[j * 50 + k] * 256.0f) * (1.0f / 256.0f)) : 0.0f;
        }
        if (t < 64) ws[WS_B1 + t] = (t < 50) ? clamp8(rintf(fb1[t] * 256.0f) * (1.0f / 256.0f)) : 0.0f;
        if (t < 16) ws[WS_B2 + t] = (t < 10) ? clamp8(rintf(fb2[t] * 256.0f) * (1.0f / 256.0f)) : 0.0f;
    } else {   // b == 51: conv weights, padded [rows][28], x256
        for (int idx = t; idx < 5600; idx += 256) {
            int cc = idx / 28, col = idx % 28;
            ws[WS_CW2 + idx] = (col < 25) ? rintf(cw2[cc * 25 + col] * 256.0f) : 0.0f;
        }
        if (t < 20) ws[WS_CB2 + t] = rintf(cb2[t] * 256.0f);
        for (int idx = t; idx < 280; idx += 256) {
            int cc = idx / 28, col = idx % 28;
            ws[WS_CW1 + idx] = (col < 25) ? rintf(cw1[cc * 25 + col] * 256.0f) : 0.0f;
        }
        if (t >= 32 && t < 42) ws[WS_CB1 + (t - 32)] = rintf(cb1[t - 32] * 256.0f);
    }
}

// ---------------- K12W: whole net, FOUR waves per image ----------------
// block=256 (4 waves), grid = NB = 2048 -> 8192 waves.
// Phase A (conv1+pool1): wave wv owns rows i=6wv..6wv+5. Lane (L<60):
//   c5=L/12, r=L%12, ii=r>>1, jh=r&1, i=6wv+ii; loop h=0,1: co=5h+c5.
//   Conflict-free (6 rows -> 2-way max); pool partner = lane L^2.
// Phase B (conv2+pool2): co = (t>>4) + 16g, g=0,1 (2nd iter t<64).
//   ch=t&1, i2=(t>>1)&7; partners t^1, t^2 in-wave.
// Phase C (fc1+fc2+softmax): wave 0 only.
__global__ __launch_bounds__(256, 4)
void k12w(const float* __restrict__ x, const float* __restrict__ ws,
          float* __restrict__ out)
{
    __shared__ __align__(16) float s_x[784];    // image; [0..320) reused as fc1in
    __shared__ __align__(16) float s_p1[1440];  // pool1 out = conv2 in

    const int t   = threadIdx.x;
    const int img = blockIdx.x;
    const int wv  = t >> 6;
    const int L   = t & 63;

    {   // input staging: quantize once, write c1in + LDS
        const float* xg = x + (size_t)img * 784;
        float* c1in_g = out + OFF_C1IN + (size_t)img * 784;
        for (int i = t; i < 784; i += 256) {
            float v = rintf(xg[i] * 256.0f) * (1.0f / 256.0f);
            s_x[i] = v;
            c1in_g[i] = v;
        }
    }
    __syncthreads();

    // ================= phase A: conv1 + pool1 (6 consecutive rows per wave) =================
    if (L < 60) {
        const int c5 = L / 12;         // 0..4: co column within half
        const int r  = L % 12;
        const int ii = r >> 1;         // 0..5
        const int jh = r & 1;          // cols [12*jh, 12*jh+12)
        const int i  = wv * 6 + ii;    // 0..23; wave-local rows consecutive

        for (int h = 0; h < 2; h++) {
            asm volatile("" ::: "memory");   // block LICM: x-window reloads per co
            const int co = h * 5 + c5;
            float wreg[28];
            {
                const float* wb = ws + WS_CW1 + co * 28;   // L1-hot, 12-lane broadcast
                #pragma unroll
                for (int k = 0; k < 7; k++) {
                    float4 v4 = *(const float4*)(wb + 4 * k);
                    wreg[4*k] = v4.x; wreg[4*k+1] = v4.y; wreg[4*k+2] = v4.z; wreg[4*k+3] = v4.w;
                }
            }
            float acc[12];
            #pragma unroll
            for (int j = 0; j < 12; j++) acc[j] = MAGIC_F;
            #pragma unroll
            for (int p = 0; p < 5; p++) {
                float xr[16];      // per-(co,p) reload — small live range
                const float* row = s_x + (i + p) * 28 + 12 * jh;
                #pragma unroll
                for (int k = 0; k < 4; k++) {
                    float4 v4 = *(const float4*)(row + 4 * k);
                    xr[4*k] = v4.x; xr[4*k+1] = v4.y; xr[4*k+2] = v4.z; xr[4*k+3] = v4.w;
                }
                #pragma unroll
                for (int q = 0; q < 5; q++) {
                    float w = wreg[p * 5 + q];
                    #pragma unroll
                    for (int j = 0; j < 12; j++)
                        acc[j] = fmaf(xr[q + j], w, acc[j]);   // mul+round+add
                }
            }
            const float C = MAGIC_F - ws[WS_CB1 + co];
            float v[12];
            #pragma unroll
            for (int j = 0; j < 12; j++) v[j] = (acc[j] - C) * (1.0f / 256.0f);

            float* gdst = out + OFF_C1OUT + (size_t)img * 5760 + co * 576 + i * 24 + 12 * jh;
            #pragma unroll
            for (int k = 0; k < 3; k++) {
                float4 st = { v[4*k], v[4*k+1], v[4*k+2], v[4*k+3] };
                *(float4*)(gdst + 4 * k) = st;
            }

            float m[6];
            #pragma unroll
            for (int j2 = 0; j2 < 6; j2++) m[j2] = fmaxf(v[2*j2], v[2*j2+1]);
            float pm[6];
            #pragma unroll
            for (int j2 = 0; j2 < 6; j2++) pm[j2] = __shfl_xor(m[j2], 2);  // partner i^1

            if ((ii & 1) == 0) {
                float pr[6];
                #pragma unroll
                for (int j2 = 0; j2 < 6; j2++)
                    pr[j2] = fmaxf(fmaxf(m[j2], pm[j2]), 0.0f);
                const int o = co * 144 + (i >> 1) * 12 + 6 * jh;
                float* g = out + OFF_C2IN + (size_t)img * 1440 + o;
                #pragma unroll
                for (int k = 0; k < 3; k++) {
                    float2 st = { pr[2*k], pr[2*k+1] };
                    *(float2*)(g + 2 * k) = st;
                    *(float2*)(s_p1 + o + 2 * k) = st;    // LDS handoff
                }
            }
        }
    }
    __syncthreads();   // s_p1 complete (all 10 ci)

    // ================= phase B: conv2 + pool2 (co = (t>>4) + 16g) =================
    const int ch = t & 1;              // ci-half
    const int i2 = (t >> 1) & 7;

    auto conv2_body = [&](int co) {
        float acc[8];
        #pragma unroll
        for (int j = 0; j < 8; j++) acc[j] = MAGIC_F;

        #pragma unroll
        for (int cc = 0; cc < 5; cc++) {
            const int ci = ch * 5 + cc;
            float wreg[28];
            {
                const float* wb = ws + WS_CW2 + (co * 10 + ci) * 28;   // L1-hot
                #pragma unroll
                for (int k = 0; k < 7; k++) {
                    float4 v4 = *(const float4*)(wb + 4 * k);
                    wreg[4*k] = v4.x; wreg[4*k+1] = v4.y; wreg[4*k+2] = v4.z; wreg[4*k+3] = v4.w;
                }
            }
            const float* xb = s_p1 + ci * 144;
            #pragma unroll
            for (int p = 0; p < 5; p++) {
                const float* row = xb + (i2 + p) * 12;
                float4 a4 = *(const float4*)(row);
                float4 b4 = *(const float4*)(row + 4);
                float4 c4 = *(const float4*)(row + 8);
                float xr[12] = { a4.x, a4.y, a4.z, a4.w, b4.x, b4.y, b4.z, b4.w,
                                 c4.x, c4.y, c4.z, c4.w };
                #pragma unroll
                for (int q = 0; q < 5; q++) {
                    float w = wreg[p * 5 + q];
                    #pragma unroll
                    for (int j = 0; j < 8; j++)
                        acc[j] = fmaf(xr[q + j], w, acc[j]);
                }
            }
        }

        float s[8];
        #pragma unroll
        for (int j = 0; j < 8; j++) s[j] = acc[j] - MAGIC_F;       // exact un-bias
        #pragma unroll
        for (int j = 0; j < 8; j++) s[j] += __shfl_xor(s[j], 1);   // other ci-half

        const float b2 = ws[WS_CB2 + co];
        float v[8];
        #pragma unroll
        for (int j = 0; j < 8; j++) v[j] = (s[j] + b2) * (1.0f / 256.0f);

        float m[4], pm[4];
        #pragma unroll
        for (int c = 0; c < 4; c++) m[c] = fmaxf(v[2*c], v[2*c+1]);
        #pragma unroll
        for (int c = 0; c < 4; c++) pm[c] = __shfl_xor(m[c], 2);   // partner i^1

        if (ch == 0) {
            float4 st0 = { v[0], v[1], v[2], v[3] };
            float4 st1 = { v[4], v[5], v[6], v[7] };
            float* cdst = out + OFF_C2OUT + (size_t)img * 1280 + co * 64 + i2 * 8;
            *(float4*)(cdst)     = st0;
            *(float4*)(cdst + 4) = st1;

            if ((i2 & 1) == 0) {
                float4 pr = { fmaxf(fmaxf(m[0], pm[0]), 0.0f),
                              fmaxf(fmaxf(m[1], pm[1]), 0.0f),
                              fmaxf(fmaxf(m[2], pm[2]), 0.0f),
                              fmaxf(fmaxf(m[3], pm[3]), 0.0f) };
                const int o = co * 16 + (i2 >> 1) * 4;
                *(float4*)(out + OFF_FC1IN + (size_t)img * 320 + o) = pr;
                float4 prc = { clamp8(pr.x), clamp8(pr.y), clamp8(pr.z), clamp8(pr.w) };
                *(float4*)(s_x + o) = prc;            // clamped fc1 input (x dead)
            }
        }
    };

    for (int co0 = t >> 4; co0 < 20; co0 += 16) {
        asm volatile("" ::: "memory");   // block LICM across iterations
        conv2_body(co0);                 // co 0..15 all threads; 16..19 on t<64
    }
    __syncthreads();   // fc1in (s_x[0..320)) complete

    // ================= phase C: fc1 + fc2 + log_softmax (wave 0 only) =================
    if (wv == 0) {
        const float* sf = s_x;
        float acc = ws[WS_B1 + L];
        #pragma unroll 8
        for (int k = 0; k < 320; k++)
            acc = fmaf(sf[k], ws[WS_WT1 + k * 64 + L], acc);   // LDS broadcast + 256B coalesced
        float o1 = rintf(clamp8(acc) * 256.0f) * (1.0f / 256.0f);
        float r1 = fmaxf(o1, 0.0f);
        if (L < 50) {
            out[OFF_FC1OUT + (size_t)img * 50 + L] = o1;
            out[OFF_FC2IN  + (size_t)img * 50 + L] = r1;
        }
        float yc = clamp8(r1);                 // valid on lanes 0..49

        float acc2 = ws[WS_B2 + (L & 15)];
        #pragma unroll 10
        for (int k = 0; k < 50; k++) {
            float yk = __shfl(yc, k);
            acc2 = fmaf(yk, ws[WS_WT2 + k * 16 + (L & 15)], acc2);
        }
        float o2 = rintf(clamp8(acc2) * 256.0f) * (1.0f / 256.0f);
        if (L < 10) out[OFF_FC2OUT + (size_t)img * 10 + L] = o2;

        float vmx = (L < 10) ? o2 : -3.0e38f;
        #pragma unroll
        for (int d = 1; d < 16; d <<= 1)
            vmx = fmaxf(vmx, __shfl_xor(vmx, d, 16));
        float e = (L < 10) ? expf(o2 - vmx) : 0.0f;
        #pragma unroll
        for (int d = 1; d < 16; d <<= 1)
            e += __shfl_xor(e, d, 16);
        float lse = vmx + logf(e);
        if (L < 10) out[OFF_LOGP + (size_t)img * 10 + L] = o2 - lse;
    }
}

extern "C" void kernel_launch(void* const* d_in, const int* in_sizes, int n_in,
                              void* d_out, int out_size, void* d_ws, size_t ws_size,
                              hipStream_t stream) {
    const float* x   = (const float*)d_in[0];
    const float* cw1 = (const float*)d_in[1];
    const float* cb1 = (const float*)d_in[2];
    const float* cw2 = (const float*)d_in[3];
    const float* cb2 = (const float*)d_in[4];
    const float* fw1 = (const float*)d_in[5];
    const float* fb1 = (const float*)d_in[6];
    const float* fw2 = (const float*)d_in[7];
    const float* fb2 = (const float*)d_in[8];
    float* o  = (float*)d_out;
    float* ws = (float*)d_ws;

    k0_prep<<<52, 256, 0, stream>>>(cw1, cb1, cw2, cb2, fw1, fb1, fw2, fb2, ws);
    k12w   <<<NB, 256, 0, stream>>>(x, ws, o);
}

// Round 19
// 154.721 us; speedup vs baseline: 1.4544x; 1.0018x over previous
//
#include <hip/hip_runtime.h>
#include <math.h>

// Fixed-point LeNet, B=2048. R28 = R27 with ONE change: fc1 k-split across
// all 4 waves. R27 post-mortem: VGPR spill fixed (FETCH 6.6->3.7MB) but
// duration flat -> spill wasn't critical-path. Latency arithmetic: at 30%
// occupancy per-block wall ~18us, and phase C is a SERIAL TAIL — wave 0
// alone issues 320 L2-latency loads (wT1=80KB>L1) in a dependent chain
// (~40 round-trips x ~250cyc ~ 4-5us) while waves 1-3 idle = ~25% of block
// lifetime. R28: each wave computes a partial over k in [80wv,80wv+80)
// (wave 0 seeds bias), partials to dead s_p1, one barrier, wave 0 reduces
// + fc2 + softmax as before. Load tail /4. Numeric reorder ~2^-9 absorbed
// by the 1/256 output grid (threshold headroom 0.0625 -> 0.158).
//
// Output layout (fp32, concatenated flat in reference return order):
//   logp[2048,10], conv1_in[2048,784], conv1_out[2048,5760],
//   conv2_in[2048,1440], conv2_out[2048,1280], fc1_in[2048,320],
//   fc1_out[2048,50], fc2_in[2048,50], fc2_out[2048,10]

#define NB 2048

#define OFF_LOGP   0
#define OFF_C1IN   (OFF_LOGP  + NB*10)
#define OFF_C1OUT  (OFF_C1IN  + NB*784)
#define OFF_C2IN   (OFF_C1OUT + NB*5760)
#define OFF_C2OUT  (OFF_C2IN  + NB*1440)
#define OFF_FC1IN  (OFF_C2OUT + NB*1280)
#define OFF_FC1OUT (OFF_FC1IN + NB*320)
#define OFF_FC2IN  (OFF_FC1OUT+ NB*50)
#define OFF_FC2OUT (OFF_FC2IN + NB*50)

#define MAGIC_F 12582912.0f   // 1.5 * 2^23

// Workspace layout (floats): pre-quantized weights, written by k0_prep.
#define WS_WT1 0         // [320][64] transposed fw1 (j>=50 -> 0)
#define WS_B1  20480     // [64]
#define WS_WT2 20544     // [50][16] transposed fw2 (j>=10 -> 0)
#define WS_B2  21344     // [16]
#define WS_CW2 21360     // [20*10][28] padded conv2 rows, quant(w)*256 (col>=25 -> 0)
#define WS_CB2 26960     // [20] quant(b)*256
#define WS_CW1 26980     // [10][28] padded conv1 rows, quant(w)*256
#define WS_CB1 27260     // [10] quant(b)*256   (total 27270 floats)

__device__ __forceinline__ float clamp8(float v) {
    return __builtin_amdgcn_fmed3f(v, -8.0f, 7.0f);
}

// ---------------- K0: weight pre-quantization (52 small blocks) ----------------
__global__ __launch_bounds__(256)
void k0_prep(const float* __restrict__ cw1, const float* __restrict__ cb1,
             const float* __restrict__ cw2, const float* __restrict__ cb2,
             const float* __restrict__ fw1, const float* __restrict__ fb1,
             const float* __restrict__ fw2, const float* __restrict__ fb2,
             float* __restrict__ ws)
{
    const int t = threadIdx.x, b = blockIdx.x;
    if (b < 50) {
        // wT1 row j=b: coalesced read fw1[b*320 + i], scattered (cheap) write.
        const float* src = fw1 + b * 320;
        for (int i = t; i < 320; i += 256)
            ws[WS_WT1 + i * 64 + b] = clamp8(rintf(src[i] * 256.0f) * (1.0f / 256.0f));
    } else if (b == 50) {
        for (int idx = t; idx < 320 * 14; idx += 256) {     // zero cols 50..63
            int i = idx / 14, j = 50 + idx % 14;
            ws[WS_WT1 + i * 64 + j] = 0.0f;
        }
        for (int idx = t; idx < 800; idx += 256) {          // wT2[50][16]
            int k = idx >> 4, j = idx & 15;
            ws[WS_WT2 + idx] = (j < 10) ? clamp8(rintf(fw2[j * 50 + k] * 256.0f) * (1.0f / 256.0f)) : 0.0f;
        }
        if (t < 64) ws[WS_B1 + t] = (t < 50) ? clamp8(rintf(fb1[t] * 256.0f) * (1.0f / 256.0f)) : 0.0f;
        if (t < 16) ws[WS_B2 + t] = (t < 10) ? clamp8(rintf(fb2[t] * 256.0f) * (1.0f / 256.0f)) : 0.0f;
    } else {   // b == 51: conv weights, padded [rows][28], x256
        for (int idx = t; idx < 5600; idx += 256) {
            int cc = idx / 28, col = idx % 28;
            ws[WS_CW2 + idx] = (col < 25) ? rintf(cw2[cc * 25 + col] * 256.0f) : 0.0f;
        }
        if (t < 20) ws[WS_CB2 + t] = rintf(cb2[t] * 256.0f);
        for (int idx = t; idx < 280; idx += 256) {
            int cc = idx / 28, col = idx % 28;
            ws[WS_CW1 + idx] = (col < 25) ? rintf(cw1[cc * 25 + col] * 256.0f) : 0.0f;
        }
        if (t >= 32 && t < 42) ws[WS_CB1 + (t - 32)] = rintf(cb1[t - 32] * 256.0f);
    }
}

// ---------------- K12W: whole net, FOUR waves per image ----------------
// block=256 (4 waves), grid = NB = 2048 -> 8192 waves.
// Phase A (conv1+pool1): wave wv owns rows i=6wv..6wv+5. Lane (L<60):
//   c5=L/12, r=L%12, ii=r>>1, jh=r&1, i=6wv+ii; loop h=0,1: co=5h+c5.
//   Conflict-free (6 rows -> 2-way max); pool partner = lane L^2.
// Phase B (conv2+pool2): co = (t>>4) + 16g, g=0,1 (2nd iter t<64).
//   ch=t&1, i2=(t>>1)&7; partners t^1, t^2 in-wave.
// Phase C (fc1 k-split over 4 waves -> LDS reduce; fc2+softmax wave 0).
__global__ __launch_bounds__(256, 4)
void k12w(const float* __restrict__ x, const float* __restrict__ ws,
          float* __restrict__ out)
{
    __shared__ __align__(16) float s_x[784];    // image; [0..320) reused as fc1in
    __shared__ __align__(16) float s_p1[1440];  // pool1 out = conv2 in; [0..256) reused fc1 partials

    const int t   = threadIdx.x;
    const int img = blockIdx.x;
    const int wv  = t >> 6;
    const int L   = t & 63;

    {   // input staging: quantize once, write c1in + LDS
        const float* xg = x + (size_t)img * 784;
        float* c1in_g = out + OFF_C1IN + (size_t)img * 784;
        for (int i = t; i < 784; i += 256) {
            float v = rintf(xg[i] * 256.0f) * (1.0f / 256.0f);
            s_x[i] = v;
            c1in_g[i] = v;
        }
    }
    __syncthreads();

    // ================= phase A: conv1 + pool1 (6 consecutive rows per wave) =================
    if (L < 60) {
        const int c5 = L / 12;         // 0..4: co column within half
        const int r  = L % 12;
        const int ii = r >> 1;         // 0..5
        const int jh = r & 1;          // cols [12*jh, 12*jh+12)
        const int i  = wv * 6 + ii;    // 0..23; wave-local rows consecutive

        for (int h = 0; h < 2; h++) {
            asm volatile("" ::: "memory");   // block LICM: x-window reloads per co
            const int co = h * 5 + c5;
            float wreg[28];
            {
                const float* wb = ws + WS_CW1 + co * 28;   // L1-hot, 12-lane broadcast
                #pragma unroll
                for (int k = 0; k < 7; k++) {
                    float4 v4 = *(const float4*)(wb + 4 * k);
                    wreg[4*k] = v4.x; wreg[4*k+1] = v4.y; wreg[4*k+2] = v4.z; wreg[4*k+3] = v4.w;
                }
            }
            float acc[12];
            #pragma unroll
            for (int j = 0; j < 12; j++) acc[j] = MAGIC_F;
            #pragma unroll
            for (int p = 0; p < 5; p++) {
                float xr[16];      // per-(co,p) reload — small live range
                const float* row = s_x + (i + p) * 28 + 12 * jh;
                #pragma unroll
                for (int k = 0; k < 4; k++) {
                    float4 v4 = *(const float4*)(row + 4 * k);
                    xr[4*k] = v4.x; xr[4*k+1] = v4.y; xr[4*k+2] = v4.z; xr[4*k+3] = v4.w;
                }
                #pragma unroll
                for (int q = 0; q < 5; q++) {
                    float w = wreg[p * 5 + q];
                    #pragma unroll
                    for (int j = 0; j < 12; j++)
                        acc[j] = fmaf(xr[q + j], w, acc[j]);   // mul+round+add
                }
            }
            const float C = MAGIC_F - ws[WS_CB1 + co];
            float v[12];
            #pragma unroll
            for (int j = 0; j < 12; j++) v[j] = (acc[j] - C) * (1.0f / 256.0f);

            float* gdst = out + OFF_C1OUT + (size_t)img * 5760 + co * 576 + i * 24 + 12 * jh;
            #pragma unroll
            for (int k = 0; k < 3; k++) {
                float4 st = { v[4*k], v[4*k+1], v[4*k+2], v[4*k+3] };
                *(float4*)(gdst + 4 * k) = st;
            }

            float m[6];
            #pragma unroll
            for (int j2 = 0; j2 < 6; j2++) m[j2] = fmaxf(v[2*j2], v[2*j2+1]);
            float pm[6];
            #pragma unroll
            for (int j2 = 0; j2 < 6; j2++) pm[j2] = __shfl_xor(m[j2], 2);  // partner i^1

            if ((ii & 1) == 0) {
                float pr[6];
                #pragma unroll
                for (int j2 = 0; j2 < 6; j2++)
                    pr[j2] = fmaxf(fmaxf(m[j2], pm[j2]), 0.0f);
                const int o = co * 144 + (i >> 1) * 12 + 6 * jh;
                float* g = out + OFF_C2IN + (size_t)img * 1440 + o;
                #pragma unroll
                for (int k = 0; k < 3; k++) {
                    float2 st = { pr[2*k], pr[2*k+1] };
                    *(float2*)(g + 2 * k) = st;
                    *(float2*)(s_p1 + o + 2 * k) = st;    // LDS handoff
                }
            }
        }
    }
    __syncthreads();   // s_p1 complete (all 10 ci)

    // ================= phase B: conv2 + pool2 (co = (t>>4) + 16g) =================
    const int ch = t & 1;              // ci-half
    const int i2 = (t >> 1) & 7;

    auto conv2_body = [&](int co) {
        float acc[8];
        #pragma unroll
        for (int j = 0; j < 8; j++) acc[j] = MAGIC_F;

        #pragma unroll
        for (int cc = 0; cc < 5; cc++) {
            const int ci = ch * 5 + cc;
            float wreg[28];
            {
                const float* wb = ws + WS_CW2 + (co * 10 + ci) * 28;   // L1-hot
                #pragma unroll
                for (int k = 0; k < 7; k++) {
                    float4 v4 = *(const float4*)(wb + 4 * k);
                    wreg[4*k] = v4.x; wreg[4*k+1] = v4.y; wreg[4*k+2] = v4.z; wreg[4*k+3] = v4.w;
                }
            }
            const float* xb = s_p1 + ci * 144;
            #pragma unroll
            for (int p = 0; p < 5; p++) {
                const float* row = xb + (i2 + p) * 12;
                float4 a4 = *(const float4*)(row);
                float4 b4 = *(const float4*)(row + 4);
                float4 c4 = *(const float4*)(row + 8);
                float xr[12] = { a4.x, a4.y, a4.z, a4.w, b4.x, b4.y, b4.z, b4.w,
                                 c4.x, c4.y, c4.z, c4.w };
                #pragma unroll
                for (int q = 0; q < 5; q++) {
                    float w = wreg[p * 5 + q];
                    #pragma unroll
                    for (int j = 0; j < 8; j++)
                        acc[j] = fmaf(xr[q + j], w, acc[j]);
                }
            }
        }

        float s[8];
        #pragma unroll
        for (int j = 0; j < 8; j++) s[j] = acc[j] - MAGIC_F;       // exact un-bias
        #pragma unroll
        for (int j = 0; j < 8; j++) s[j] += __shfl_xor(s[j], 1);   // other ci-half

        const float b2 = ws[WS_CB2 + co];
        float v[8];
        #pragma unroll
        for (int j = 0; j < 8; j++) v[j] = (s[j] + b2) * (1.0f / 256.0f);

        float m[4], pm[4];
        #pragma unroll
        for (int c = 0; c < 4; c++) m[c] = fmaxf(v[2*c], v[2*c+1]);
        #pragma unroll
        for (int c = 0; c < 4; c++) pm[c] = __shfl_xor(m[c], 2);   // partner i^1

        if (ch == 0) {
            float4 st0 = { v[0], v[1], v[2], v[3] };
            float4 st1 = { v[4], v[5], v[6], v[7] };
            float* cdst = out + OFF_C2OUT + (size_t)img * 1280 + co * 64 + i2 * 8;
            *(float4*)(cdst)     = st0;
            *(float4*)(cdst + 4) = st1;

            if ((i2 & 1) == 0) {
                float4 pr = { fmaxf(fmaxf(m[0], pm[0]), 0.0f),
                              fmaxf(fmaxf(m[1], pm[1]), 0.0f),
                              fmaxf(fmaxf(m[2], pm[2]), 0.0f),
                              fmaxf(fmaxf(m[3], pm[3]), 0.0f) };
                const int o = co * 16 + (i2 >> 1) * 4;
                *(float4*)(out + OFF_FC1IN + (size_t)img * 320 + o) = pr;
                float4 prc = { clamp8(pr.x), clamp8(pr.y), clamp8(pr.z), clamp8(pr.w) };
                *(float4*)(s_x + o) = prc;            // clamped fc1 input (x dead)
            }
        }
    };

    for (int co0 = t >> 4; co0 < 20; co0 += 16) {
        asm volatile("" ::: "memory");   // block LICM across iterations
        conv2_body(co0);                 // co 0..15 all threads; 16..19 on t<64
    }
    __syncthreads();   // fc1in (s_x[0..320)) complete

    // ================= phase C: fc1 k-split over 4 waves =================
    // Each wave: partial dot over k in [80*wv, 80*wv+80); wave 0 seeds bias.
    // s_p1[0..256) is dead (conv2 consumed it) -> partial buffer.
    {
        const float* sf = s_x;
        float part = (wv == 0) ? ws[WS_B1 + L] : 0.0f;
        const int k0 = wv * 80;
        #pragma unroll 8
        for (int k = k0; k < k0 + 80; k++)
            part = fmaf(sf[k], ws[WS_WT1 + k * 64 + L], part);   // LDS bcast + 256B coalesced
        s_p1[wv * 64 + L] = part;
    }
    __syncthreads();   // partials complete

    // ---- wave 0: reduce partials, then fc2 + log_softmax (proven body) ----
    if (wv == 0) {
        float acc = s_p1[L] + s_p1[64 + L] + s_p1[128 + L] + s_p1[192 + L];
        float o1 = rintf(clamp8(acc) * 256.0f) * (1.0f / 256.0f);
        float r1 = fmaxf(o1, 0.0f);
        if (L < 50) {
            out[OFF_FC1OUT + (size_t)img * 50 + L] = o1;
            out[OFF_FC2IN  + (size_t)img * 50 + L] = r1;
        }
        float yc = clamp8(r1);                 // valid on lanes 0..49

        float acc2 = ws[WS_B2 + (L & 15)];
        #pragma unroll 10
        for (int k = 0; k < 50; k++) {
            float yk = __shfl(yc, k);
            acc2 = fmaf(yk, ws[WS_WT2 + k * 16 + (L & 15)], acc2);
        }
        float o2 = rintf(clamp8(acc2) * 256.0f) * (1.0f / 256.0f);
        if (L < 10) out[OFF_FC2OUT + (size_t)img * 10 + L] = o2;

        float vmx = (L < 10) ? o2 : -3.0e38f;
        #pragma unroll
        for (int d = 1; d < 16; d <<= 1)
            vmx = fmaxf(vmx, __shfl_xor(vmx, d, 16));
        float e = (L < 10) ? expf(o2 - vmx) : 0.0f;
        #pragma unroll
        for (int d = 1; d < 16; d <<= 1)
            e += __shfl_xor(e, d, 16);
        float lse = vmx + logf(e);
        if (L < 10) out[OFF_LOGP + (size_t)img * 10 + L] = o2 - lse;
    }
}

extern "C" void kernel_launch(void* const* d_in, const int* in_sizes, int n_in,
                              void* d_out, int out_size, void* d_ws, size_t ws_size,
                              hipStream_t stream) {
    const float* x   = (const float*)d_in[0];
    const float* cw1 = (const float*)d_in[1];
    const float* cb1 = (const float*)d_in[2];
    const float* cw2 = (const float*)d_in[3];
    const float* cb2 = (const float*)d_in[4];
    const float* fw1 = (const float*)d_in[5];
    const float* fb1 = (const float*)d_in[6];
    const float* fw2 = (const float*)d_in[7];
    const float* fb2 = (const float*)d_in[8];
    float* o  = (float*)d_out;
    float* ws = (float*)d_ws;

    k0_prep<<<52, 256, 0, stream>>>(cw1, cb1, cw2, cb2, fw1, fb1, fw2, fb2, ws);
    k12w   <<<NB, 256, 0, stream>>>(x, ws, o);
}